// Round 3
// baseline (524.741 us; speedup 1.0000x reference)
//
#include <hip/hip_runtime.h>
#include <hip/hip_cooperative_groups.h>

namespace cg = cooperative_groups;

#define BATCH 16384
#define DIM   4096

typedef __bf16 bf16x8 __attribute__((ext_vector_type(8)));
typedef float  f32x4  __attribute__((ext_vector_type(4)));
typedef unsigned short u16x8 __attribute__((ext_vector_type(8)));
typedef unsigned short u16x4 __attribute__((ext_vector_type(4)));

// ---- workspace layout (float offsets) ----
#define WS_ROWSUM 0         // 16384
#define WS_MED    16384     // 1
#define WS_NPART  16400     // 512*2
#define WS_A2PART 18432     // 256*64
#define WS_A3PART 34816     // 256*128
#define WS_CPART  67584     // 512*128 (per-block col sum[64] then sumsq[64])
#define WS_R      133120    // 16384*64 fp32
#define WS_H3B    1181696   // 16384*64 bf16 (as ushort) = 524288 floats
#define WS_WTIN   1705984   // 64*4096 bf16 (as ushort)
#define WS_WTO    1837056   // 3 * 4096*64 bf16

__device__ __forceinline__ unsigned short f2bf(float f){
  union { float f; unsigned u; } v; v.f = f;
  unsigned r = v.u + 0x7FFFu + ((v.u >> 16) & 1u);
  return (unsigned short)(r >> 16);
}

// L0: weight transpose/bf16 prep (blocks 0..1023) + row sums of x (blocks 1024..5119).
__global__ __launch_bounds__(256) void k_prep_rowsum(
    const float* __restrict__ x, const float* __restrict__ Win,
    const float* __restrict__ Wpi, const float* __restrict__ Wm,
    const float* __restrict__ Wth, float* __restrict__ ws){
  int b = blockIdx.x, t = threadIdx.x;
  if (b < 1024) {
    unsigned short* wtin = (unsigned short*)(ws + WS_WTIN);
    unsigned short* wto  = (unsigned short*)(ws + WS_WTO);
    int idx = (b * 256 + t) * 4;
    if (idx < 262144) {
      int k = idx >> 6, n = idx & 63;           // 4 consecutive n, same k
      float4 v = *(const float4*)(Win + idx);
      wtin[(n+0) * 4096 + k] = f2bf(v.x);
      wtin[(n+1) * 4096 + k] = f2bf(v.y);
      wtin[(n+2) * 4096 + k] = f2bf(v.z);
      wtin[(n+3) * 4096 + k] = f2bf(v.w);
    } else {
      int r = idx - 262144;
      int m = r >> 18, rr = r & 262143;
      int k = rr >> 12, n = rr & 4095;          // 4 consecutive n, same k
      const float* W = (m == 0) ? Wpi : ((m == 1) ? Wm : Wth);
      float4 v = *(const float4*)(W + rr);
      unsigned short* dst = wto + m * 262144 + n * 64 + k;
      dst[0] = f2bf(v.x); dst[64] = f2bf(v.y); dst[128] = f2bf(v.z); dst[192] = f2bf(v.w);
    }
  } else {
    int w = t >> 6, lane = t & 63;
    int row = (b - 1024) * 4 + w;
    const float4* xr = (const float4*)(x + (size_t)row * DIM);
    float s = 0.f;
    #pragma unroll
    for (int i = 0; i < 16; ++i) {
      float4 v = xr[lane + 64 * i];
      s += (v.x + v.y) + (v.z + v.w);
    }
    #pragma unroll
    for (int m = 32; m; m >>= 1) s += __shfl_xor(s, m);
    if (lane == 0) ws[WS_ROWSUM + row] = s;
  }
}

// L1: exact lower median of 16384 positive floats via 3-pass MSD radix (bits 12/12/8).
// One block, 1024 threads; keys LDS-resident. Positive-float bit order is monotone.
__global__ __launch_bounds__(1024) void k_median(float* __restrict__ ws){
  __shared__ unsigned keys[16384];
  __shared__ int hist[4096];
  __shared__ int scanbuf[1024];
  __shared__ int selBin, selRank;
  int t = threadIdx.x, lane = t & 63;

  for (int i = t; i < 16384; i += 1024) keys[i] = __float_as_uint(ws[WS_ROWSUM + i]);
  for (int i = t; i < 4096; i += 1024) hist[i] = 0;
  __syncthreads();

  auto scanFind = [&](int target) {
    int s = hist[4*t] + hist[4*t+1] + hist[4*t+2] + hist[4*t+3];
    scanbuf[t] = s;
    __syncthreads();
    for (int off = 1; off < 1024; off <<= 1) {
      int v = scanbuf[t];
      int a = (t >= off) ? scanbuf[t - off] : 0;
      __syncthreads();
      scanbuf[t] = v + a;
      __syncthreads();
    }
    int acc = scanbuf[t] - s;   // exclusive prefix before my 4 bins
    #pragma unroll
    for (int j = 0; j < 4; ++j) {
      int c = hist[4*t + j];
      if (acc <= target && target < acc + c) { selBin = 4*t + j; selRank = target - acc; }
      acc += c;
    }
    __syncthreads();
  };

  // pass 1: top 12 bits — values cluster, so wave-aggregate the shared atomics.
  for (int i = t; i < 16384; i += 1024) {
    unsigned key = keys[i] >> 20;
    unsigned long long unclaimed = __ballot(1);
    int cnt = 0; bool leader = false;
    while (true) {
      int src = (int)(__ffsll((unsigned long long)unclaimed)) - 1;
      unsigned k0 = (unsigned)__shfl((int)key, src);
      unsigned long long eq = __ballot(k0 == key);
      if (k0 == key) { leader = (lane == src); cnt = (int)__popcll(eq); break; }
      unclaimed &= ~eq;
    }
    if (leader) atomicAdd(&hist[key], cnt);
  }
  __syncthreads();
  scanFind(8191);                       // lower median = 0-based rank 8191
  unsigned B1 = (unsigned)selBin; int r1 = selRank;
  __syncthreads();
  for (int i = t; i < 4096; i += 1024) hist[i] = 0;
  __syncthreads();
  // pass 2: mid 12 bits among matching
  for (int i = t; i < 16384; i += 1024) {
    unsigned u = keys[i];
    if ((u >> 20) == B1) atomicAdd(&hist[(u >> 8) & 0xFFF], 1);
  }
  __syncthreads();
  scanFind(r1);
  unsigned B2 = (unsigned)selBin; int r2 = selRank;
  __syncthreads();
  for (int i = t; i < 4096; i += 1024) hist[i] = 0;
  __syncthreads();
  // pass 3: low 8 bits among matching
  unsigned hi24 = (B1 << 12) | B2;
  for (int i = t; i < 16384; i += 1024) {
    unsigned u = keys[i];
    if ((u >> 8) == hi24) atomicAdd(&hist[u & 0xFF], 1);
  }
  __syncthreads();
  scanFind(r2);
  if (t == 0) {
    unsigned bits = (B1 << 20) | (B2 << 8) | (unsigned)selBin;
    ws[WS_MED] = __uint_as_float(bits);
  }
}

// L2: fused norm + R = norm @ W_in, per-block column sum/sumsq of R, global norm stats.
// BM=32 rows, grid 512, 2-deep prefetch, ONE barrier per K-step.
__global__ __launch_bounds__(512) void k_passB(const float* __restrict__ x, float* __restrict__ ws){
  __shared__ __align__(16) char Ab[2 * 4096];   // [2][32 rows][64 k] bf16, XOR-swizzled 16B chunks
  __shared__ __align__(16) char Bb[2 * 8192];   // [2][64 n   ][64 k] bf16, XOR-swizzled
  __shared__ float ainv_s[32];
  __shared__ float redn[8][2];
  __shared__ float cpart[2][64], cqpart[2][64];

  const unsigned short* wtin = (const unsigned short*)(ws + WS_WTIN);
  int tid = threadIdx.x;
  int r0 = blockIdx.x * 32;
  float med = ws[WS_MED];
  if (tid < 32) ainv_s[tid] = med / ws[WS_ROWSUM + r0 + tid];
  __syncthreads();

  int w = tid >> 6, lane = tid & 63;
  int li = lane & 15, u = lane >> 4;
  int wrb = (w & 1) * 16;       // wave A-row base
  int wc  = (w >> 1) * 16;      // wave B-col base

  int xrow = tid >> 4;                // 0..31
  int xcol0 = (tid & 15) * 4;         // 0..60
  int wn = tid >> 3, wkc = tid & 7;   // weight stage: row n, 16B chunk
  float ainv = ainv_s[xrow];

  f32x4 acc = (f32x4){0.f, 0.f, 0.f, 0.f};
  float nsum = 0.f, nsq = 0.f;
  float4 xa0, xa1; u16x8 wv0, wv1;

  auto LOADT = [&](int tt, float4& xv, u16x8& wq){
    int coff = tt * 64;
    xv = *(const float4*)(x + (size_t)(r0 + xrow) * DIM + coff + xcol0);
    wq = *(const u16x8*)(wtin + (size_t)wn * DIM + coff + wkc * 8);
  };
  auto WRITET = [&](int buf, const float4& xv, const u16x8& wq){
    float n0 = __logf(fmaf(xv.x, ainv, 1.f));
    float n1 = __logf(fmaf(xv.y, ainv, 1.f));
    float n2 = __logf(fmaf(xv.z, ainv, 1.f));
    float n3 = __logf(fmaf(xv.w, ainv, 1.f));
    nsum += (n0 + n1) + (n2 + n3);
    nsq  += (n0*n0 + n1*n1) + (n2*n2 + n3*n3);
    u16x4 p = { f2bf(n0), f2bf(n1), f2bf(n2), f2bf(n3) };
    int c = xcol0 >> 3, sub = (xcol0 >> 2) & 1;
    *(u16x4*)(Ab + buf * 4096 + xrow * 128 + ((c ^ (xrow & 7)) << 4) + sub * 8) = p;
    *(u16x8*)(Bb + buf * 8192 + wn * 128 + ((wkc ^ (wn & 7)) << 4)) = wq;
  };
  int arow = wrb + li, brow = wc + li;
  auto DOMFMA = [&](int p){
    const char* Au = Ab + p * 4096;
    const char* Bu = Bb + p * 8192;
    #pragma unroll
    for (int kk = 0; kk < 2; ++kk) {
      bf16x8 aF = *(const bf16x8*)(Au + arow * 128 + (((kk * 4 + u) ^ (arow & 7)) << 4));
      bf16x8 bF = *(const bf16x8*)(Bu + brow * 128 + (((kk * 4 + u) ^ (brow & 7)) << 4));
      acc = __builtin_amdgcn_mfma_f32_16x16x32_bf16(bF, aF, acc, 0, 0, 0);
    }
  };

  LOADT(0, xa0, wv0);
  WRITET(0, xa0, wv0);
  LOADT(1, xa1, wv1);
  __syncthreads();
  for (int t = 0; t < 64; t += 2) {
    // even step: compute buf0 (tile t), write tile t+1 into buf1, load tile t+2
    if (t + 2 < 64) LOADT(t + 2, xa0, wv0);
    WRITET(1, xa1, wv1);
    DOMFMA(0);
    __syncthreads();
    // odd step: compute buf1 (tile t+1), write tile t+2 into buf0, load tile t+3
    if (t + 3 < 64) LOADT(t + 3, xa1, wv1);
    if (t + 2 < 64) WRITET(0, xa0, wv0);
    DOMFMA(1);
    __syncthreads();
  }

  // store R: each lane one float4 (row via li, 4 consecutive cols via u*4)
  float* R = ws + WS_R;
  *(f32x4*)(R + (size_t)(r0 + wrb + li) * 64 + wc + u * 4) = acc;

  // per-block column partial sums/sumsq from acc (reduce over 16 rows = li lanes)
  float s0 = acc[0], s1 = acc[1], s2 = acc[2], s3 = acc[3];
  float q0 = acc[0]*acc[0], q1 = acc[1]*acc[1], q2 = acc[2]*acc[2], q3 = acc[3]*acc[3];
  #pragma unroll
  for (int m = 1; m < 16; m <<= 1) {
    s0 += __shfl_xor(s0, m); s1 += __shfl_xor(s1, m);
    s2 += __shfl_xor(s2, m); s3 += __shfl_xor(s3, m);
    q0 += __shfl_xor(q0, m); q1 += __shfl_xor(q1, m);
    q2 += __shfl_xor(q2, m); q3 += __shfl_xor(q3, m);
  }
  if (li == 0) {
    int cb = wc + u * 4;
    cpart[w & 1][cb + 0] = s0; cpart[w & 1][cb + 1] = s1;
    cpart[w & 1][cb + 2] = s2; cpart[w & 1][cb + 3] = s3;
    cqpart[w & 1][cb + 0] = q0; cqpart[w & 1][cb + 1] = q1;
    cqpart[w & 1][cb + 2] = q2; cqpart[w & 1][cb + 3] = q3;
  }
  #pragma unroll
  for (int m = 32; m; m >>= 1) { nsum += __shfl_xor(nsum, m); nsq += __shfl_xor(nsq, m); }
  if (lane == 0) { redn[w][0] = nsum; redn[w][1] = nsq; }
  __syncthreads();
  if (tid < 64) {
    ws[WS_CPART + blockIdx.x * 128 + tid]      = cpart[0][tid] + cpart[1][tid];
    ws[WS_CPART + blockIdx.x * 128 + 64 + tid] = cqpart[0][tid] + cqpart[1][tid];
  }
  if (tid == 0) {
    float S = 0.f, Q = 0.f;
    for (int i = 0; i < 8; ++i) { S += redn[i][0]; Q += redn[i][1]; }
    ws[WS_NPART + blockIdx.x * 2]     = S;
    ws[WS_NPART + blockIdx.x * 2 + 1] = Q;
  }
}

// L3: cooperative mid-chain. Grid 256 x 256 threads; 64 rows/block held in LDS end-to-end.
// Stage A: BN1+relu -> a2 (LDS) + partials; sync; Stage B: BN2+relu -> a3 (LDS) + partials;
// sync; Stage C: BN3+relu -> h3 bf16 global.
__global__ __launch_bounds__(256) void k_mid(
    const float* __restrict__ g1, const float* __restrict__ bt1,
    const float* __restrict__ Wenc, const float* __restrict__ benc,
    const float* __restrict__ g2, const float* __restrict__ bt2,
    const float* __restrict__ Wdec, const float* __restrict__ bdec,
    const float* __restrict__ g3, const float* __restrict__ bt3,
    float* __restrict__ ws){
  cg::grid_group grid = cg::this_grid();
  __shared__ float scv[64], ccv[64];
  __shared__ float h1[64][65];
  __shared__ float wraw[2112];          // Wenc as [64][33] or Wdec as [32][65]
  __shared__ float a2s[64][33];
  __shared__ float a3s[64][65];
  __shared__ float sred[4][64], qred[4][64];
  __shared__ float sigred[4][2];
  __shared__ float sig2s;
  __shared__ float red3[128];
  int t = threadIdx.x, lane = t & 63, w4 = t >> 6;
  int r0 = blockIdx.x * 64;
  const float* R = ws + WS_R;

  // ---- BN1 constants ----
  {
    float s = 0.f, q = 0.f;
    for (int b = t; b < 512; b += 256) { s += ws[WS_NPART + b * 2]; q += ws[WS_NPART + b * 2 + 1]; }
    #pragma unroll
    for (int m = 32; m; m >>= 1) { s += __shfl_xor(s, m); q += __shfl_xor(q, m); }
    if (lane == 0) { sigred[w4][0] = s; sigred[w4][1] = q; }
  }
  {
    int col = t & 63, grp = t >> 6;
    float S = 0.f, Q = 0.f;
    for (int b = grp * 128; b < grp * 128 + 128; ++b) {
      S += ws[WS_CPART + b * 128 + col];
      Q += ws[WS_CPART + b * 128 + 64 + col];
    }
    sred[grp][col] = S; qred[grp][col] = Q;
  }
  for (int i = t; i < 2048; i += 256) wraw[(i >> 5) * 33 + (i & 31)] = Wenc[i];
  __syncthreads();
  if (t == 0) {
    double Sn = (double)sigred[0][0] + sigred[1][0] + sigred[2][0] + sigred[3][0];
    double Qn = (double)sigred[0][1] + sigred[1][1] + sigred[2][1] + sigred[3][1];
    double N = 67108864.0;
    sig2s = (float)((Qn - Sn * Sn / N) / (N - 1.0));
  }
  __syncthreads();
  if (t < 64) {
    float Sc = sred[0][t] + sred[1][t] + sred[2][t] + sred[3][t];
    float Qc = qred[0][t] + qred[1][t] + qred[2][t] + qred[3][t];
    float cm = Sc * (1.f / 16384.f);
    float cv = Qc * (1.f / 16384.f) - cm * cm;
    float sc = g1[t] * rsqrtf(cv + sig2s * 1e-5f);
    scv[t] = sc; ccv[t] = bt1[t] - cm * sc;
  }
  __syncthreads();
  // h1 = relu(BN1(R))
  for (int i = t; i < 4096; i += 256) {
    int row = i >> 6, col = i & 63;
    float v = fmaf(R[(size_t)(r0 + row) * 64 + col], scv[col], ccv[col]);
    h1[row][col] = fmaxf(v, 0.f);
  }
  __syncthreads();
  // a2 = h1 @ Wenc + benc
  {
    int row = t & 63, cb = t >> 6;
    float a[8];
    #pragma unroll
    for (int j = 0; j < 8; ++j) a[j] = benc[cb * 8 + j];
    for (int k = 0; k < 64; ++k) {
      float hv = h1[row][k];
      #pragma unroll
      for (int j = 0; j < 8; ++j) a[j] = fmaf(hv, wraw[k * 33 + cb * 8 + j], a[j]);
    }
    #pragma unroll
    for (int j = 0; j < 8; ++j) a2s[row][cb * 8 + j] = a[j];
    #pragma unroll
    for (int j = 0; j < 8; ++j) {
      float s = a[j], q = a[j] * a[j];
      #pragma unroll
      for (int m = 32; m; m >>= 1) { s += __shfl_xor(s, m); q += __shfl_xor(q, m); }
      if (lane == 0) {
        int c = cb * 8 + j;
        ws[WS_A2PART + blockIdx.x * 64 + c * 2]     = s;
        ws[WS_A2PART + blockIdx.x * 64 + c * 2 + 1] = q;
      }
    }
  }
  __threadfence();
  grid.sync();

  // ---- Stage B ----
  {
    float* s2 = &sred[0][0];  // 256 floats
    float* q2 = &qred[0][0];
    int col = t & 31, grp = t >> 5;
    float S = 0.f, Q = 0.f;
    for (int b = grp * 32; b < grp * 32 + 32; ++b) {
      S += ws[WS_A2PART + b * 64 + col * 2];
      Q += ws[WS_A2PART + b * 64 + col * 2 + 1];
    }
    s2[grp * 32 + col] = S; q2[grp * 32 + col] = Q;
  }
  for (int i = t; i < 2048; i += 256) wraw[(i >> 6) * 65 + (i & 63)] = Wdec[i];
  __syncthreads();
  if (t < 32) {
    float* s2 = &sred[0][0];
    float* q2 = &qred[0][0];
    float Sc = 0.f, Qc = 0.f;
    #pragma unroll
    for (int g = 0; g < 8; ++g) { Sc += s2[g * 32 + t]; Qc += q2[g * 32 + t]; }
    float cm = Sc * (1.f / 16384.f);
    float cv = Qc * (1.f / 16384.f) - cm * cm;
    float sc = g2[t] * rsqrtf(cv + 1e-5f);
    scv[t] = sc; ccv[t] = bt2[t] - cm * sc;
  }
  __syncthreads();
  // h2 in place
  for (int i = t; i < 2048; i += 256) {
    int row = i >> 5, col = i & 31;
    float v = fmaf(a2s[row][col], scv[col], ccv[col]);
    a2s[row][col] = fmaxf(v, 0.f);
  }
  __syncthreads();
  // a3 = h2 @ Wdec + bdec
  {
    int row = t & 63, cb = t >> 6;
    float a[16];
    #pragma unroll
    for (int j = 0; j < 16; ++j) a[j] = bdec[cb * 16 + j];
    for (int k = 0; k < 32; ++k) {
      float hv = a2s[row][k];
      #pragma unroll
      for (int j = 0; j < 16; ++j) a[j] = fmaf(hv, wraw[k * 65 + cb * 16 + j], a[j]);
    }
    #pragma unroll
    for (int j = 0; j < 16; ++j) a3s[row][cb * 16 + j] = a[j];
    #pragma unroll
    for (int j = 0; j < 16; ++j) {
      float s = a[j], q = a[j] * a[j];
      #pragma unroll
      for (int m = 32; m; m >>= 1) { s += __shfl_xor(s, m); q += __shfl_xor(q, m); }
      if (lane == 0) {
        int c = cb * 16 + j;
        ws[WS_A3PART + blockIdx.x * 128 + c * 2]     = s;
        ws[WS_A3PART + blockIdx.x * 128 + c * 2 + 1] = q;
      }
    }
  }
  __threadfence();
  grid.sync();

  // ---- Stage C ----
  if (t < 128) {
    float s = 0.f;
    for (int b = 0; b < 256; ++b) s += ws[WS_A3PART + b * 128 + t];
    red3[t] = s;
  }
  __syncthreads();
  if (t < 64) {
    float S = red3[2 * t], Q = red3[2 * t + 1];
    float cm = S * (1.f / 16384.f);
    float cv = Q * (1.f / 16384.f) - cm * cm;
    float sc = g3[t] * rsqrtf(cv + 1e-5f);
    scv[t] = sc; ccv[t] = bt3[t] - cm * sc;
  }
  __syncthreads();
  unsigned short* h3 = (unsigned short*)(ws + WS_H3B);
  for (int i = t; i < 4096; i += 256) {
    int row = i >> 6, col = i & 63;
    float v = fmaf(a3s[row][col], scv[col], ccv[col]);
    h3[(size_t)(r0 + row) * 64 + col] = f2bf(fmaxf(v, 0.f));
  }
}

// L4: heads. Reads h3 bf16 straight into A-fragments; out = act(h3 @ W + b).
// 128 rows x 256 cols per block, grid 2048, 512 threads.
__global__ __launch_bounds__(512) void k_out(const float* __restrict__ bpi, const float* __restrict__ bm,
                      const float* __restrict__ bth, float* __restrict__ out,
                      float* __restrict__ ws){
  __shared__ __align__(16) char WB[256 * 128];   // [256 n][64 k] bf16, XOR-swizzled
  int t = threadIdx.x;
  int bx = blockIdx.x;
  int rb = bx >> 4, cb = bx & 15;
  int r0 = rb * 128, c0 = cb * 256;
  int w = t >> 6, lane = t & 63;
  int u = lane >> 4, li = lane & 15;

  const unsigned short* h3 = (const unsigned short*)(ws + WS_H3B);
  int arow = r0 + w * 16 + li;
  bf16x8 aF0 = *(const bf16x8*)(h3 + (size_t)arow * 64 + u * 8);
  bf16x8 aF1 = *(const bf16x8*)(h3 + (size_t)arow * 64 + 32 + u * 8);

  const unsigned short* wto = (const unsigned short*)(ws + WS_WTO);
  for (int m = 0; m < 3; ++m) {
    __syncthreads();
    const unsigned short* src = wto + (size_t)m * 262144 + (size_t)c0 * 64;
    for (int ch = t; ch < 2048; ch += 512) {
      int n = ch >> 3, kc = ch & 7;
      u16x8 vchunk = *(const u16x8*)(src + n * 64 + kc * 8);
      *(u16x8*)(WB + n * 128 + ((kc ^ (n & 7)) << 4)) = vchunk;
    }
    __syncthreads();
    const float* bias = (m == 0) ? bpi : ((m == 1) ? bm : bth);
    float* po = out + (size_t)m * 67108864;
    for (int cg = 0; cg < 16; ++cg) {
      int n = cg * 16 + li;
      bf16x8 bF0 = *(const bf16x8*)(WB + n * 128 + (((0 + u) ^ (n & 7)) << 4));
      bf16x8 bF1 = *(const bf16x8*)(WB + n * 128 + (((4 + u) ^ (n & 7)) << 4));
      f32x4 d = (f32x4){0.f, 0.f, 0.f, 0.f};
      d = __builtin_amdgcn_mfma_f32_16x16x32_bf16(bF0, aF0, d, 0, 0, 0);
      d = __builtin_amdgcn_mfma_f32_16x16x32_bf16(bF1, aF1, d, 0, 0, 0);
      int colb = c0 + cg * 16 + u * 4;
      f32x4 bv = *(const f32x4*)(bias + colb);
      f32x4 z;
      #pragma unroll
      for (int r = 0; r < 4; ++r) {
        float zz = d[r] + bv[r];
        z[r] = (m == 0) ? (1.f / (1.f + __expf(-zz))) : __expf(zz);
      }
      __builtin_nontemporal_store(z, (f32x4*)(po + (size_t)arow * 4096 + colb));
    }
  }
}

extern "C" void kernel_launch(void* const* d_in, const int* in_sizes, int n_in,
                              void* d_out, int out_size, void* d_ws, size_t ws_size,
                              hipStream_t stream) {
  const float* x    = (const float*)d_in[0];
  const float* Win  = (const float*)d_in[1];
  // d_in[2] = b_in: cancels through BN1, unused.
  const float* g1   = (const float*)d_in[3];
  const float* bt1  = (const float*)d_in[4];
  const float* Wenc = (const float*)d_in[5];
  const float* benc = (const float*)d_in[6];
  const float* g2   = (const float*)d_in[7];
  const float* bt2  = (const float*)d_in[8];
  const float* Wdec = (const float*)d_in[9];
  const float* bdec = (const float*)d_in[10];
  const float* g3   = (const float*)d_in[11];
  const float* bt3  = (const float*)d_in[12];
  const float* Wpi  = (const float*)d_in[13];
  const float* bpi  = (const float*)d_in[14];
  const float* Wm   = (const float*)d_in[15];
  const float* bm   = (const float*)d_in[16];
  const float* Wth  = (const float*)d_in[17];
  const float* bth  = (const float*)d_in[18];
  float* ws  = (float*)d_ws;
  float* out = (float*)d_out;

  hipLaunchKernelGGL(k_prep_rowsum, dim3(5120), dim3(256),  0, stream, x, Win, Wpi, Wm, Wth, ws);
  hipLaunchKernelGGL(k_median,      dim3(1),    dim3(1024), 0, stream, ws);
  hipLaunchKernelGGL(k_passB,       dim3(512),  dim3(512),  0, stream, x, ws);
  void* args[] = { (void*)&g1, (void*)&bt1, (void*)&Wenc, (void*)&benc,
                   (void*)&g2, (void*)&bt2, (void*)&Wdec, (void*)&bdec,
                   (void*)&g3, (void*)&bt3, (void*)&ws };
  hipLaunchCooperativeKernel((const void*)k_mid, dim3(256), dim3(256), args, 0, stream);
  hipLaunchKernelGGL(k_out,         dim3(2048), dim3(512),  0, stream, bpi, bm, bth, out, ws);
}

// Round 5
// 448.622 us; speedup vs baseline: 1.1697x; 1.1697x over previous
//
#include <hip/hip_runtime.h>

#define BATCH 16384
#define DIM   4096

typedef __bf16 bf16x8 __attribute__((ext_vector_type(8)));
typedef float  f32x4  __attribute__((ext_vector_type(4)));
typedef unsigned short u16x8 __attribute__((ext_vector_type(8)));
typedef unsigned short u16x4 __attribute__((ext_vector_type(4)));

// ---- workspace layout (float offsets) ----
#define WS_ROWSUM 0         // 16384
#define WS_MED    16384     // 1
#define WS_NPART  16400     // 512*2
#define WS_SC3    17536     // 64
#define WS_CC3    17600     // 64
#define WS_A2PART 18432     // 256*64
#define WS_A3PART 34816     // 256*128
#define WS_CPART  67584     // 512*128 (per-block col sum[64] then sumsq[64])
#define WS_R      133120    // 16384*64 fp32
#define WS_A2     1181696   // 16384*32 fp32
#define WS_A3     1705984   // 16384*64 fp32
#define WS_WTIN   2754560   // 64*4096 bf16 (as ushort)
#define WS_WTO    2885632   // 3 * 4096*64 bf16

__device__ __forceinline__ unsigned short f2bf(float f){
  union { float f; unsigned u; } v; v.f = f;
  unsigned r = v.u + 0x7FFFu + ((v.u >> 16) & 1u);
  return (unsigned short)(r >> 16);
}

// L0: weight transpose/bf16 prep via LDS (blocks 0..255, coalesced 128B+ writes)
//     + row sums of x (blocks 256..4351).
__global__ __launch_bounds__(256) void k_prep_rowsum(
    const float* __restrict__ x, const float* __restrict__ Win,
    const float* __restrict__ Wpi, const float* __restrict__ Wm,
    const float* __restrict__ Wth, float* __restrict__ ws){
  int b = blockIdx.x, t = threadIdx.x;
  if (b < 256) {
    __shared__ unsigned short tile[64][72];   // 72 -> 144B row stride (16B aligned)
    if (b < 64) {
      // wtin[n][k0+kk] = bf16(Win[k0+kk][n]), k-tile of 64
      int k0 = b * 64;
      int n = t & 63, kb = t >> 6;
      #pragma unroll
      for (int i = 0; i < 16; ++i) {
        int kk = kb * 16 + i;
        tile[n][kk] = f2bf(Win[(size_t)(k0 + kk) * 64 + n]);
      }
      __syncthreads();
      unsigned short* wtin = (unsigned short*)(ws + WS_WTIN);
      int c = t & 7;
      #pragma unroll
      for (int p = 0; p < 2; ++p) {
        int nn = (t >> 3) + p * 32;
        u16x8 v = *(const u16x8*)&tile[nn][c * 8];
        *(u16x8*)(wtin + (size_t)nn * 4096 + k0 + c * 8) = v;
      }
    } else {
      // wto[m][n0+nn][k] = bf16(W[k][n0+nn]), n-tile of 64
      int bm = (b - 64) >> 6;
      int n0 = ((b - 64) & 63) * 64;
      const float* W = (bm == 0) ? Wpi : ((bm == 1) ? Wm : Wth);
      int nn = t & 63, kb = t >> 6;
      #pragma unroll
      for (int i = 0; i < 16; ++i) {
        int k = kb * 16 + i;
        tile[nn][k] = f2bf(W[(size_t)k * 4096 + n0 + nn]);
      }
      __syncthreads();
      unsigned short* wto = (unsigned short*)(ws + WS_WTO);
      int c = t & 7;
      #pragma unroll
      for (int p = 0; p < 2; ++p) {
        int nn2 = (t >> 3) + p * 32;
        u16x8 v = *(const u16x8*)&tile[nn2][c * 8];
        *(u16x8*)(wto + (size_t)bm * 262144 + (size_t)(n0 + nn2) * 64 + c * 8) = v;
      }
    }
  } else {
    int w = t >> 6, lane = t & 63;
    int row = (b - 256) * 4 + w;
    const float4* xr = (const float4*)(x + (size_t)row * DIM);
    float s = 0.f;
    #pragma unroll
    for (int i = 0; i < 16; ++i) {
      float4 v = xr[lane + 64 * i];
      s += (v.x + v.y) + (v.z + v.w);
    }
    #pragma unroll
    for (int m = 32; m; m >>= 1) s += __shfl_xor(s, m);
    if (lane == 0) ws[WS_ROWSUM + row] = s;
  }
}

// L1: exact lower median of 16384 positive floats via 3-pass MSD radix (bits 12/12/8).
__global__ __launch_bounds__(1024) void k_median(float* __restrict__ ws){
  __shared__ unsigned keys[16384];
  __shared__ int hist[4096];
  __shared__ int scanbuf[1024];
  __shared__ int selBin, selRank;
  int t = threadIdx.x, lane = t & 63;

  for (int i = t; i < 16384; i += 1024) keys[i] = __float_as_uint(ws[WS_ROWSUM + i]);
  for (int i = t; i < 4096; i += 1024) hist[i] = 0;
  __syncthreads();

  auto scanFind = [&](int target) {
    int s = hist[4*t] + hist[4*t+1] + hist[4*t+2] + hist[4*t+3];
    scanbuf[t] = s;
    __syncthreads();
    for (int off = 1; off < 1024; off <<= 1) {
      int v = scanbuf[t];
      int a = (t >= off) ? scanbuf[t - off] : 0;
      __syncthreads();
      scanbuf[t] = v + a;
      __syncthreads();
    }
    int acc = scanbuf[t] - s;
    #pragma unroll
    for (int j = 0; j < 4; ++j) {
      int c = hist[4*t + j];
      if (acc <= target && target < acc + c) { selBin = 4*t + j; selRank = target - acc; }
      acc += c;
    }
    __syncthreads();
  };

  // pass 1: top 12 bits — wave-aggregated shared atomics (keys cluster tightly).
  for (int i = t; i < 16384; i += 1024) {
    unsigned key = keys[i] >> 20;
    unsigned long long unclaimed = __ballot(1);
    int cnt = 0; bool leader = false;
    while (true) {
      int src = (int)(__ffsll((unsigned long long)unclaimed)) - 1;
      unsigned k0 = (unsigned)__shfl((int)key, src);
      unsigned long long eq = __ballot(k0 == key);
      if (k0 == key) { leader = (lane == src); cnt = (int)__popcll(eq); break; }
      unclaimed &= ~eq;
    }
    if (leader) atomicAdd(&hist[key], cnt);
  }
  __syncthreads();
  scanFind(8191);
  unsigned B1 = (unsigned)selBin; int r1 = selRank;
  __syncthreads();
  for (int i = t; i < 4096; i += 1024) hist[i] = 0;
  __syncthreads();
  for (int i = t; i < 16384; i += 1024) {
    unsigned u = keys[i];
    if ((u >> 20) == B1) atomicAdd(&hist[(u >> 8) & 0xFFF], 1);
  }
  __syncthreads();
  scanFind(r1);
  unsigned B2 = (unsigned)selBin; int r2 = selRank;
  __syncthreads();
  for (int i = t; i < 4096; i += 1024) hist[i] = 0;
  __syncthreads();
  unsigned hi24 = (B1 << 12) | B2;
  for (int i = t; i < 16384; i += 1024) {
    unsigned u = keys[i];
    if ((u >> 8) == hi24) atomicAdd(&hist[u & 0xFF], 1);
  }
  __syncthreads();
  scanFind(r2);
  if (t == 0) {
    unsigned bits = (B1 << 20) | (B2 << 8) | (unsigned)selBin;
    ws[WS_MED] = __uint_as_float(bits);
  }
}

// L2: fused norm + R = norm @ W_in, per-block column sum/sumsq of R, global norm stats.
// BM=32 rows, grid 512, 2-deep prefetch, one barrier per K-step.
// Register-set pairing: tile j lives in set j&1. Verified structure from round 3.
__global__ __launch_bounds__(512) void k_passB(const float* __restrict__ x, float* __restrict__ ws){
  __shared__ __align__(16) char Ab[2 * 4096];
  __shared__ __align__(16) char Bb[2 * 8192];
  __shared__ float ainv_s[32];
  __shared__ float redn[8][2];
  __shared__ float cpart[2][64], cqpart[2][64];

  const unsigned short* wtin = (const unsigned short*)(ws + WS_WTIN);
  int tid = threadIdx.x;
  int r0 = blockIdx.x * 32;
  float med = ws[WS_MED];
  if (tid < 32) ainv_s[tid] = med / ws[WS_ROWSUM + r0 + tid];
  __syncthreads();

  int w = tid >> 6, lane = tid & 63;
  int li = lane & 15, u = lane >> 4;
  int wrb = (w & 1) * 16;
  int wc  = (w >> 1) * 16;

  int xrow = tid >> 4;
  int xcol0 = (tid & 15) * 4;
  int wn = tid >> 3, wkc = tid & 7;
  float ainv = ainv_s[xrow];

  f32x4 acc = (f32x4){0.f, 0.f, 0.f, 0.f};
  float nsum = 0.f, nsq = 0.f;
  float4 xa0, xa1; u16x8 wv0, wv1;

  auto LOADT = [&](int tt, float4& xv, u16x8& wq){
    int coff = tt * 64;
    xv = *(const float4*)(x + (size_t)(r0 + xrow) * DIM + coff + xcol0);
    wq = *(const u16x8*)(wtin + (size_t)wn * DIM + coff + wkc * 8);
  };
  auto WRITET = [&](int buf, const float4& xv, const u16x8& wq){
    float n0 = __logf(fmaf(xv.x, ainv, 1.f));
    float n1 = __logf(fmaf(xv.y, ainv, 1.f));
    float n2 = __logf(fmaf(xv.z, ainv, 1.f));
    float n3 = __logf(fmaf(xv.w, ainv, 1.f));
    nsum += (n0 + n1) + (n2 + n3);
    nsq  += (n0*n0 + n1*n1) + (n2*n2 + n3*n3);
    u16x4 p = { f2bf(n0), f2bf(n1), f2bf(n2), f2bf(n3) };
    int c = xcol0 >> 3, sub = (xcol0 >> 2) & 1;
    *(u16x4*)(Ab + buf * 4096 + xrow * 128 + ((c ^ (xrow & 7)) << 4) + sub * 8) = p;
    *(u16x8*)(Bb + buf * 8192 + wn * 128 + ((wkc ^ (wn & 7)) << 4)) = wq;
  };
  int arow = wrb + li, brow = wc + li;
  auto DOMFMA = [&](int p){
    const char* Au = Ab + p * 4096;
    const char* Bu = Bb + p * 8192;
    #pragma unroll
    for (int kk = 0; kk < 2; ++kk) {
      bf16x8 aF = *(const bf16x8*)(Au + arow * 128 + (((kk * 4 + u) ^ (arow & 7)) << 4));
      bf16x8 bF = *(const bf16x8*)(Bu + brow * 128 + (((kk * 4 + u) ^ (brow & 7)) << 4));
      acc = __builtin_amdgcn_mfma_f32_16x16x32_bf16(bF, aF, acc, 0, 0, 0);
    }
  };

  LOADT(0, xa0, wv0);
  WRITET(0, xa0, wv0);
  LOADT(1, xa1, wv1);
  __syncthreads();
  for (int t = 0; t < 64; t += 2) {
    // phase 1: compute tile t (buf0); stage tile t+1 (xa1 -> buf1); load tile t+2 -> xa0
    if (t + 2 < 64) LOADT(t + 2, xa0, wv0);
    WRITET(1, xa1, wv1);
    DOMFMA(0);
    __syncthreads();
    // phase 2: compute tile t+1 (buf1); stage tile t+2 (xa0 -> buf0); load tile t+3 -> xa1
    if (t + 3 < 64) LOADT(t + 3, xa1, wv1);
    if (t + 2 < 64) WRITET(0, xa0, wv0);
    DOMFMA(1);
    __syncthreads();
  }

  float* R = ws + WS_R;
  *(f32x4*)(R + (size_t)(r0 + wrb + li) * 64 + wc + u * 4) = acc;

  float s0 = acc[0], s1 = acc[1], s2 = acc[2], s3 = acc[3];
  float q0 = acc[0]*acc[0], q1 = acc[1]*acc[1], q2 = acc[2]*acc[2], q3 = acc[3]*acc[3];
  #pragma unroll
  for (int m = 1; m < 16; m <<= 1) {
    s0 += __shfl_xor(s0, m); s1 += __shfl_xor(s1, m);
    s2 += __shfl_xor(s2, m); s3 += __shfl_xor(s3, m);
    q0 += __shfl_xor(q0, m); q1 += __shfl_xor(q1, m);
    q2 += __shfl_xor(q2, m); q3 += __shfl_xor(q3, m);
  }
  if (li == 0) {
    int cb = wc + u * 4;
    cpart[w & 1][cb + 0] = s0; cpart[w & 1][cb + 1] = s1;
    cpart[w & 1][cb + 2] = s2; cpart[w & 1][cb + 3] = s3;
    cqpart[w & 1][cb + 0] = q0; cqpart[w & 1][cb + 1] = q1;
    cqpart[w & 1][cb + 2] = q2; cqpart[w & 1][cb + 3] = q3;
  }
  #pragma unroll
  for (int m = 32; m; m >>= 1) { nsum += __shfl_xor(nsum, m); nsq += __shfl_xor(nsq, m); }
  if (lane == 0) { redn[w][0] = nsum; redn[w][1] = nsq; }
  __syncthreads();
  if (tid < 64) {
    ws[WS_CPART + blockIdx.x * 128 + tid]      = cpart[0][tid] + cpart[1][tid];
    ws[WS_CPART + blockIdx.x * 128 + 64 + tid] = cqpart[0][tid] + cqpart[1][tid];
  }
  if (tid == 0) {
    float S = 0.f, Q = 0.f;
    for (int i = 0; i < 8; ++i) { S += redn[i][0]; Q += redn[i][1]; }
    ws[WS_NPART + blockIdx.x * 2]     = S;
    ws[WS_NPART + blockIdx.x * 2 + 1] = Q;
  }
}

// L3: BN1 finalize + h1 = relu(BN1(R)), a2 = h1 @ W_enc + b_enc, a2 partials.
__global__ __launch_bounds__(256) void k_layer1(const float* __restrict__ g1, const float* __restrict__ bt1,
                         const float* __restrict__ Wenc, const float* __restrict__ benc,
                         float* __restrict__ ws){
  __shared__ float sc1[64], cc1[64];
  __shared__ float h1[64][65];
  __shared__ float we[64][33];
  __shared__ float sred[4][64], qred[4][64];
  __shared__ float sigred[4][2];
  __shared__ float sig2s;
  int t = threadIdx.x, lane = t & 63, w4 = t >> 6;

  {
    float s = 0.f, q = 0.f;
    for (int b = t; b < 512; b += 256) { s += ws[WS_NPART + b * 2]; q += ws[WS_NPART + b * 2 + 1]; }
    #pragma unroll
    for (int m = 32; m; m >>= 1) { s += __shfl_xor(s, m); q += __shfl_xor(q, m); }
    if (lane == 0) { sigred[w4][0] = s; sigred[w4][1] = q; }
  }
  {
    int col = t & 63, grp = t >> 6;
    float S = 0.f, Q = 0.f;
    for (int b = grp * 128; b < grp * 128 + 128; ++b) {
      S += ws[WS_CPART + b * 128 + col];
      Q += ws[WS_CPART + b * 128 + 64 + col];
    }
    sred[grp][col] = S; qred[grp][col] = Q;
  }
  for (int i = t; i < 2048; i += 256) we[i >> 5][i & 31] = Wenc[i];
  __syncthreads();
  if (t == 0) {
    double Sn = (double)sigred[0][0] + sigred[1][0] + sigred[2][0] + sigred[3][0];
    double Qn = (double)sigred[0][1] + sigred[1][1] + sigred[2][1] + sigred[3][1];
    double N = 67108864.0;
    sig2s = (float)((Qn - Sn * Sn / N) / (N - 1.0));
  }
  __syncthreads();
  if (t < 64) {
    float Sc = sred[0][t] + sred[1][t] + sred[2][t] + sred[3][t];
    float Qc = qred[0][t] + qred[1][t] + qred[2][t] + qred[3][t];
    float cm = Sc * (1.f / 16384.f);
    float cv = Qc * (1.f / 16384.f) - cm * cm;
    float sc = g1[t] * rsqrtf(cv + sig2s * 1e-5f);
    sc1[t] = sc; cc1[t] = bt1[t] - cm * sc;
  }
  __syncthreads();

  int r0 = blockIdx.x * 64;
  const float* R = ws + WS_R;
  for (int i = t; i < 4096; i += 256) {
    int row = i >> 6, col = i & 63;
    float v = fmaf(R[(size_t)(r0 + row) * 64 + col], sc1[col], cc1[col]);
    h1[row][col] = fmaxf(v, 0.f);
  }
  __syncthreads();
  int row = t & 63, cb = t >> 6;
  float a[8];
  #pragma unroll
  for (int j = 0; j < 8; ++j) a[j] = benc[cb * 8 + j];
  for (int k = 0; k < 64; ++k) {
    float hv = h1[row][k];
    #pragma unroll
    for (int j = 0; j < 8; ++j) a[j] = fmaf(hv, we[k][cb * 8 + j], a[j]);
  }
  float* A2 = ws + WS_A2;
  #pragma unroll
  for (int j = 0; j < 8; ++j) A2[(size_t)(r0 + row) * 32 + cb * 8 + j] = a[j];
  #pragma unroll
  for (int j = 0; j < 8; ++j) {
    float s = a[j], q = a[j] * a[j];
    #pragma unroll
    for (int m = 32; m; m >>= 1) { s += __shfl_xor(s, m); q += __shfl_xor(q, m); }
    if (lane == 0) {
      int c = cb * 8 + j;
      ws[WS_A2PART + blockIdx.x * 64 + c * 2]     = s;
      ws[WS_A2PART + blockIdx.x * 64 + c * 2 + 1] = q;
    }
  }
}

// L4: BN2 finalize + h2 = relu(BN2(a2)), a3 = h2 @ W_dec + b_dec, a3 partials.
__global__ __launch_bounds__(256) void k_layer2(const float* __restrict__ g2, const float* __restrict__ bt2,
                         const float* __restrict__ Wdec, const float* __restrict__ bdec,
                         float* __restrict__ ws){
  __shared__ float h2[64][33];
  __shared__ float wd[32][65];
  __shared__ float sc2[32], cc2[32];
  __shared__ float sred2[8][32], qred2[8][32];
  int t = threadIdx.x, lane = t & 63;
  {
    int col = t & 31, grp = t >> 5;
    float S = 0.f, Q = 0.f;
    for (int b = grp * 32; b < grp * 32 + 32; ++b) {
      S += ws[WS_A2PART + b * 64 + col * 2];
      Q += ws[WS_A2PART + b * 64 + col * 2 + 1];
    }
    sred2[grp][col] = S; qred2[grp][col] = Q;
  }
  for (int i = t; i < 2048; i += 256) wd[i >> 6][i & 63] = Wdec[i];
  __syncthreads();
  if (t < 32) {
    float Sc = 0.f, Qc = 0.f;
    #pragma unroll
    for (int g = 0; g < 8; ++g) { Sc += sred2[g][t]; Qc += qred2[g][t]; }
    float cm = Sc * (1.f / 16384.f);
    float cv = Qc * (1.f / 16384.f) - cm * cm;
    float sc = g2[t] * rsqrtf(cv + 1e-5f);
    sc2[t] = sc; cc2[t] = bt2[t] - cm * sc;
  }
  __syncthreads();
  int r0 = blockIdx.x * 64;
  const float* A2 = ws + WS_A2;
  for (int i = t; i < 2048; i += 256) {
    int row = i >> 5, col = i & 31;
    float v = fmaf(A2[(size_t)(r0 + row) * 32 + col], sc2[col], cc2[col]);
    h2[row][col] = fmaxf(v, 0.f);
  }
  __syncthreads();
  int row = t & 63, cb = t >> 6;
  float a[16];
  #pragma unroll
  for (int j = 0; j < 16; ++j) a[j] = bdec[cb * 16 + j];
  for (int k = 0; k < 32; ++k) {
    float hv = h2[row][k];
    #pragma unroll
    for (int j = 0; j < 16; ++j) a[j] = fmaf(hv, wd[k][cb * 16 + j], a[j]);
  }
  float* A3 = ws + WS_A3;
  #pragma unroll
  for (int j = 0; j < 16; ++j) A3[(size_t)(r0 + row) * 64 + cb * 16 + j] = a[j];
  #pragma unroll
  for (int j = 0; j < 16; ++j) {
    float s = a[j], q = a[j] * a[j];
    #pragma unroll
    for (int m = 32; m; m >>= 1) { s += __shfl_xor(s, m); q += __shfl_xor(q, m); }
    if (lane == 0) {
      int c = cb * 16 + j;
      ws[WS_A3PART + blockIdx.x * 128 + c * 2]     = s;
      ws[WS_A3PART + blockIdx.x * 128 + c * 2 + 1] = q;
    }
  }
}

// L5: reduce a3 partials -> BN3 scale/shift.
__global__ void k_red3(const float* __restrict__ g3, const float* __restrict__ bt3, float* __restrict__ ws){
  __shared__ float red[128];
  int t = threadIdx.x;
  if (t < 128) {
    float s = 0.f;
    for (int b = 0; b < 256; ++b) s += ws[WS_A3PART + b * 128 + t];
    red[t] = s;
  }
  __syncthreads();
  if (t < 64) {
    float S = red[2 * t], Q = red[2 * t + 1];
    float cm = S * (1.f / 16384.f);
    float cv = Q * (1.f / 16384.f) - cm * cm;
    float sc = g3[t] * rsqrtf(cv + 1e-5f);
    ws[WS_SC3 + t] = sc; ws[WS_CC3 + t] = bt3[t] - cm * sc;
  }
}

// L6: heads. h3 = relu(BN3(a3)) in-register; out = act(h3 @ W + b).
// PLAIN cached stores: adjacent cg iterations fill full 128B L2 lines.
__global__ __launch_bounds__(256) void k_out(const float* __restrict__ bpi, const float* __restrict__ bm,
                      const float* __restrict__ bth, float* __restrict__ out,
                      float* __restrict__ ws){
  __shared__ __align__(16) char WB[256 * 128];   // [256 n][64 k] bf16, XOR-swizzled
  int t = threadIdx.x;
  int bx = blockIdx.x;
  int rb = bx >> 4, cb = bx & 15;
  int r0 = rb * 64, c0 = cb * 256;
  int w = t >> 6, lane = t & 63;
  int u = lane >> 4, li = lane & 15;

  const float* A3 = ws + WS_A3;
  const float* SC = ws + WS_SC3;
  const float* CC = ws + WS_CC3;
  int arow = r0 + w * 16 + li;
  const float4* a3p = (const float4*)(A3 + (size_t)arow * 64);
  bf16x8 aF[2];
  #pragma unroll
  for (int h = 0; h < 2; ++h) {
    float4 v0 = a3p[h * 8 + u * 2];
    float4 v1 = a3p[h * 8 + u * 2 + 1];
    int kb = h * 32 + u * 8;
    u16x8 uu;
    uu[0] = f2bf(fmaxf(fmaf(v0.x, SC[kb+0], CC[kb+0]), 0.f));
    uu[1] = f2bf(fmaxf(fmaf(v0.y, SC[kb+1], CC[kb+1]), 0.f));
    uu[2] = f2bf(fmaxf(fmaf(v0.z, SC[kb+2], CC[kb+2]), 0.f));
    uu[3] = f2bf(fmaxf(fmaf(v0.w, SC[kb+3], CC[kb+3]), 0.f));
    uu[4] = f2bf(fmaxf(fmaf(v1.x, SC[kb+4], CC[kb+4]), 0.f));
    uu[5] = f2bf(fmaxf(fmaf(v1.y, SC[kb+5], CC[kb+5]), 0.f));
    uu[6] = f2bf(fmaxf(fmaf(v1.z, SC[kb+6], CC[kb+6]), 0.f));
    uu[7] = f2bf(fmaxf(fmaf(v1.w, SC[kb+7], CC[kb+7]), 0.f));
    aF[h] = __builtin_bit_cast(bf16x8, uu);
  }

  const unsigned short* wto = (const unsigned short*)(ws + WS_WTO);
  for (int m = 0; m < 3; ++m) {
    __syncthreads();
    const unsigned short* src = wto + (size_t)m * 262144 + (size_t)c0 * 64;
    for (int ch = t; ch < 2048; ch += 256) {
      int n = ch >> 3, kc = ch & 7;
      u16x8 vchunk = *(const u16x8*)(src + n * 64 + kc * 8);
      *(u16x8*)(WB + n * 128 + ((kc ^ (n & 7)) << 4)) = vchunk;
    }
    __syncthreads();
    const float* bias = (m == 0) ? bpi : ((m == 1) ? bm : bth);
    float* po = out + (size_t)m * 67108864;
    for (int cg = 0; cg < 16; ++cg) {
      int n = cg * 16 + li;
      bf16x8 bF0 = *(const bf16x8*)(WB + n * 128 + (((0 + u) ^ (n & 7)) << 4));
      bf16x8 bF1 = *(const bf16x8*)(WB + n * 128 + (((4 + u) ^ (n & 7)) << 4));
      f32x4 d = (f32x4){0.f, 0.f, 0.f, 0.f};
      d = __builtin_amdgcn_mfma_f32_16x16x32_bf16(bF0, aF[0], d, 0, 0, 0);
      d = __builtin_amdgcn_mfma_f32_16x16x32_bf16(bF1, aF[1], d, 0, 0, 0);
      int colb = c0 + cg * 16 + u * 4;
      f32x4 bv = *(const f32x4*)(bias + colb);
      f32x4 z;
      #pragma unroll
      for (int r = 0; r < 4; ++r) {
        float zz = d[r] + bv[r];
        z[r] = (m == 0) ? (1.f / (1.f + __expf(-zz))) : __expf(zz);
      }
      *(f32x4*)(po + (size_t)arow * 4096 + colb) = z;
    }
  }
}

extern "C" void kernel_launch(void* const* d_in, const int* in_sizes, int n_in,
                              void* d_out, int out_size, void* d_ws, size_t ws_size,
                              hipStream_t stream) {
  const float* x    = (const float*)d_in[0];
  const float* Win  = (const float*)d_in[1];
  // d_in[2] = b_in: cancels through BN1, unused.
  const float* g1   = (const float*)d_in[3];
  const float* bt1  = (const float*)d_in[4];
  const float* Wenc = (const float*)d_in[5];
  const float* benc = (const float*)d_in[6];
  const float* g2   = (const float*)d_in[7];
  const float* bt2  = (const float*)d_in[8];
  const float* Wdec = (const float*)d_in[9];
  const float* bdec = (const float*)d_in[10];
  const float* g3   = (const float*)d_in[11];
  const float* bt3  = (const float*)d_in[12];
  const float* Wpi  = (const float*)d_in[13];
  const float* bpi  = (const float*)d_in[14];
  const float* Wm   = (const float*)d_in[15];
  const float* bm   = (const float*)d_in[16];
  const float* Wth  = (const float*)d_in[17];
  const float* bth  = (const float*)d_in[18];
  float* ws  = (float*)d_ws;
  float* out = (float*)d_out;

  hipLaunchKernelGGL(k_prep_rowsum, dim3(4352), dim3(256),  0, stream, x, Win, Wpi, Wm, Wth, ws);
  hipLaunchKernelGGL(k_median,      dim3(1),    dim3(1024), 0, stream, ws);
  hipLaunchKernelGGL(k_passB,       dim3(512),  dim3(512),  0, stream, x, ws);
  hipLaunchKernelGGL(k_layer1,      dim3(256),  dim3(256),  0, stream, g1, bt1, Wenc, benc, ws);
  hipLaunchKernelGGL(k_layer2,      dim3(256),  dim3(256),  0, stream, g2, bt2, Wdec, bdec, ws);
  hipLaunchKernelGGL(k_red3,        dim3(1),    dim3(256),  0, stream, g3, bt3, ws);
  hipLaunchKernelGGL(k_out,         dim3(4096), dim3(256),  0, stream, bpi, bm, bth, out, ws);
}